// Round 4
// baseline (1979.012 us; speedup 1.0000x reference)
//
#include <hip/hip_runtime.h>
#include <hip/hip_bf16.h>

constexpr int Bn  = 8;
constexpr int Np  = 2048;
constexpr int KNN = 32;

typedef __attribute__((ext_vector_type(8))) short bf16x8;
typedef __attribute__((ext_vector_type(4))) float f32x4;

__device__ static inline void gll16(const void* g, void* l) {
  __builtin_amdgcn_global_load_lds((const __attribute__((address_space(1))) void*)g,
                                   (__attribute__((address_space(3))) void*)l, 16, 0, 0);
}

__device__ static inline unsigned short f2bf(float x) {
  union { __hip_bfloat16 h; unsigned short u; } cv; cv.h = __float2bfloat16(x); return cv.u;
}
__device__ static inline float bf2f(unsigned short u) {
  union { __hip_bfloat16 h; unsigned short u; } cv; cv.u = u; return __bfloat162float(cv.h);
}

// ------------------------------------------------------------- helpers ----
__global__ __launch_bounds__(256)
void cvt_bf16_kernel(const float* __restrict__ s, __hip_bfloat16* __restrict__ d, int n) {
  int i = blockIdx.x * 256 + threadIdx.x;
  if (i < n) d[i] = __float2bfloat16(s[i]);
}

__global__ __launch_bounds__(256)
void xpose_kernel(const float* __restrict__ x, float* __restrict__ xt) {
  int i = blockIdx.x * 256 + threadIdx.x;   // over B*N
  int b = i >> 11, n = i & 2047;
  const float* p = x + (long)b * 3 * Np + n;
  xt[(long)i * 4 + 0] = p[0];
  xt[(long)i * 4 + 1] = p[Np];
  xt[(long)i * 4 + 2] = p[2 * Np];
  xt[(long)i * 4 + 3] = 0.f;
}

template<int C, int CP>
__global__ __launch_bounds__(256)
void sq_kernel(const float* __restrict__ f, float* __restrict__ out) {
  int i = blockIdx.x * 256 + threadIdx.x;   // over B*N
  const float* p = f + (long)i * CP;
  float s = 0.f;
#pragma unroll
  for (int c = 0; c < C; ++c) s += p[c] * p[c];
  out[i] = s;
}

// -------------------------------------------------- fp32 dist GEMM ----
// C[i][j] = sqB[j] - 2 * sum_k A[i][k]*B[j][k]   (A,B row-major [rows][K])
__global__ __launch_bounds__(256)
void dist_kernel(const float* __restrict__ A, int lda, long sA,
                 float* __restrict__ C, long sC,
                 const float* __restrict__ sqB, int Kd) {
  int bz = blockIdx.z;
  A += (long)bz * sA;
  C += (long)bz * sC;
  sqB += (long)bz * Np;
  int i0 = blockIdx.y * 128, j0 = blockIdx.x * 128;
  __shared__ float As[8][128];
  __shared__ float Bs[8][128];
  float acc[8][8];
#pragma unroll
  for (int a = 0; a < 8; ++a)
#pragma unroll
    for (int b2 = 0; b2 < 8; ++b2) acc[a][b2] = 0.f;
  int t = threadIdx.x;
  int tx = t & 15, ty = t >> 4;
  for (int k0 = 0; k0 < Kd; k0 += 8) {
    {
      int ii = t >> 1, kk = (t & 1) * 4;
#pragma unroll
      for (int u = 0; u < 4; ++u) {
        int kg = k0 + kk + u;
        As[kk + u][ii] = (kg < Kd) ? A[(long)(i0 + ii) * lda + kg] : 0.f;
        Bs[kk + u][ii] = (kg < Kd) ? A[(long)(j0 + ii) * lda + kg] : 0.f;
      }
    }
    __syncthreads();
#pragma unroll
    for (int kk = 0; kk < 8; ++kk) {
      float av[8], bv[8];
#pragma unroll
      for (int u = 0; u < 8; ++u) av[u] = As[kk][ty * 8 + u];
#pragma unroll
      for (int u = 0; u < 8; ++u) bv[u] = Bs[kk][tx * 8 + u];
#pragma unroll
      for (int a = 0; a < 8; ++a)
#pragma unroll
        for (int b2 = 0; b2 < 8; ++b2) acc[a][b2] += av[a] * bv[b2];
    }
    __syncthreads();
  }
#pragma unroll
  for (int a = 0; a < 8; ++a) {
    int i = i0 + ty * 8 + a;
#pragma unroll
    for (int b2 = 0; b2 < 8; ++b2) {
      int j = j0 + tx * 8 + b2;
      C[(long)i * Np + j] = sqB[j] - 2.f * acc[a][b2];
    }
  }
}

// -------------------------------------------------------------- topk ----
// One wave per row. Keys packed (ordered_float_bits << 32) | index so a
// single u64 compare encodes (dist asc, index asc). Per-lane bitonic sort
// of 32 keys, LDS spill (interleaved, conflict-free), then 32 pop rounds.
__global__ __launch_bounds__(64)
void topk_kernel(const float* __restrict__ D, int* __restrict__ idxOut) {
  long row = (long)blockIdx.y * Np + blockIdx.x;
  const float* rowp = D + row * Np;
  int lane = threadIdx.x;
  __shared__ unsigned long long buf[64 * 33];  // [i][lane] interleaved + pad

  unsigned long long key[32];
  const float4* rp = (const float4*)(rowp + lane * 32);
#pragma unroll
  for (int j4 = 0; j4 < 8; ++j4) {
    float4 f4 = rp[j4];
    float fv[4] = {f4.x, f4.y, f4.z, f4.w};
#pragma unroll
    for (int u = 0; u < 4; ++u) {
      int m = lane * 32 + j4 * 4 + u;
      unsigned b = __float_as_uint(fv[u]);
      unsigned ou = (b & 0x80000000u) ? ~b : (b | 0x80000000u);
      key[j4 * 4 + u] = ((unsigned long long)ou << 32) | (unsigned)m;
    }
  }
  // bitonic sort ascending
#pragma unroll
  for (int k = 2; k <= 32; k <<= 1) {
#pragma unroll
    for (int j = k >> 1; j > 0; j >>= 1) {
#pragma unroll
      for (int i = 0; i < 32; ++i) {
        int l = i ^ j;
        if (l > i) {
          bool up = ((i & k) == 0);
          unsigned long long a = key[i], c = key[l];
          bool swp = up ? (a > c) : (a < c);
          unsigned long long lo = swp ? c : a;
          unsigned long long hi = swp ? a : c;
          key[i] = lo; key[l] = hi;
        }
      }
    }
  }
#pragma unroll
  for (int i = 0; i < 32; ++i) buf[i * 64 + lane] = key[i];

  unsigned long long h = key[0];
  int p = 1;
  int res = 0;
  for (int t = 0; t < KNN; ++t) {
    unsigned hh = (unsigned)(h >> 32), hl = (unsigned)h;
    unsigned g = hh;
#pragma unroll
    for (int off = 32; off > 0; off >>= 1)
      g = min(g, (unsigned)__shfl_xor((int)g, off));
    unsigned lo = (hh == g) ? hl : 0xFFFFFFFFu;
#pragma unroll
    for (int off = 32; off > 0; off >>= 1)
      lo = min(lo, (unsigned)__shfl_xor((int)lo, off));
    if (lane == t) res = (int)lo;
    if (hh == g && hl == lo) {
      h = buf[p * 64 + lane];
      ++p;
    }
  }
  if (lane < KNN) idxOut[row * KNN + lane] = res;
}

// -------------------------------------------------------------- bias ----
// bias[n][o] = sum_c (W1b - W1a)[o][c] * feat[n][c]  (the folded center term)
// Block = 256 thr = 4 waves; each wave does 8 points; lane = o.
template<int CIN, int CP>
__global__ __launch_bounds__(256)
void biasker(const float* __restrict__ feat, const float* __restrict__ w1,
             float* __restrict__ bias) {
  __shared__ float wd[64][CIN + 1];
  int tid = threadIdx.x;
  for (int e = tid; e < 64 * CIN; e += 256) {
    int o = e / CIN, c = e - o * CIN;
    wd[o][c] = w1[o * 2 * CIN + CIN + c] - w1[o * 2 * CIN + c];
  }
  __syncthreads();
  int wv = tid >> 6, o = tid & 63;
  float wr_[CIN];
#pragma unroll
  for (int c = 0; c < CIN; ++c) wr_[c] = wd[o][c];
  long base = (long)blockIdx.y * Np + blockIdx.x * 32 + wv * 8;
  for (int p = 0; p < 8; ++p) {
    const float* fr = feat + (base + p) * CP;   // wave-uniform -> s_load
    float acc = 0.f;
#pragma unroll
    for (int c = 0; c < CIN; ++c) acc = fmaf(wr_[c], fr[c], acc);
    bias[(base + p) * 64 + o] = acc;
  }
}

// ---------------------------------------------------------- edgeconv ----
// One wave = 2 points; lane = (half, k-neighbor). Neighbor feature row in
// VGPRs; weight rows wave-uniform (s_load). h1 staged once via padded LDS.
// h1[o] = W1a.nbr + bias (center term folded); bn+lrelu; h2 = W2.h1; bn+
// lrelu; max over k via LDS columns.
template<int CIN, int CP>
__global__ __launch_bounds__(64)
void edgeconv2(const float* __restrict__ feat, const int* __restrict__ idx,
               const float* __restrict__ bias,
               const float* __restrict__ w1, const float* __restrict__ bn1,
               const float* __restrict__ w2, const float* __restrict__ bn2,
               float* __restrict__ fout, __hip_bfloat16* __restrict__ xcseg) {
  __shared__ float h1s[2][32][66];   // pad 66: writes 4-way (free-ish), reads 2-way
  __shared__ float biasS[2][64];
  int l = threadIdx.x, h = l >> 5, k = l & 31;
  long pb = (long)blockIdx.y * Np;
  int n = blockIdx.x * 2 + h;
  int nbk = idx[(pb + n) * KNN + k];

  float nbrm[CP];
  {
    const float4* fr4 = (const float4*)(feat + (pb + nbk) * CP);
#pragma unroll
    for (int c4 = 0; c4 < CP / 4; ++c4) {
      float4 v4 = fr4[c4];
      nbrm[c4 * 4 + 0] = v4.x; nbrm[c4 * 4 + 1] = v4.y;
      nbrm[c4 * 4 + 2] = v4.z; nbrm[c4 * 4 + 3] = v4.w;
    }
  }
  biasS[h][k]      = bias[(pb + n) * 64 + k];
  biasS[h][k + 32] = bias[(pb + n) * 64 + 32 + k];
  __syncthreads();

#pragma unroll 2
  for (int o = 0; o < 64; ++o) {
    const float* wr = w1 + o * 2 * CIN;   // wave-uniform -> s_load
    float acc = biasS[h][o];
#pragma unroll
    for (int c = 0; c < CIN; ++c) acc = fmaf(wr[c], nbrm[c], acc);
    float sc = bn1[o] * rsqrtf(bn1[192 + o] + 1e-5f);
    float sh = bn1[64 + o] - bn1[128 + o] * sc;
    float xv = acc * sc + sh;
    h1s[h][k][o] = fmaxf(xv, 0.2f * xv);   // lrelu
  }
  float h1r[64];
#pragma unroll
  for (int c = 0; c < 64; ++c) h1r[c] = h1s[h][k][c];   // own row (lgkm-ordered)
#pragma unroll 2
  for (int o = 0; o < 64; ++o) {
    const float* wr = w2 + o * 64;        // wave-uniform -> s_load
    float acc = 0.f;
#pragma unroll
    for (int c = 0; c < 64; ++c) acc = fmaf(wr[c], h1r[c], acc);
    float sc = bn2[o] * rsqrtf(bn2[192 + o] + 1e-5f);
    float sh = bn2[64 + o] - bn2[128 + o] * sc;
    float xv = acc * sc + sh;
    h1s[h][k][o] = fmaxf(xv, 0.2f * xv);   // reuse buffer for h2
  }
  __syncthreads();
#pragma unroll
  for (int p = 0; p < 2; ++p) {
    float m = -3.4e38f;
#pragma unroll
    for (int k2 = 0; k2 < 32; ++k2) m = fmaxf(m, h1s[p][k2][l]);
    int n2 = blockIdx.x * 2 + p;
    if (fout) fout[(pb + n2) * 64 + l] = m;
    xcseg[(pb + n2) * 192 + l] = __float2bfloat16(m);
  }
}

// ------------------------------------------------------ bf16 TN GEMM ----
// D[m][n] = sum_k A[m][k]*B[n][k]; A: Ma x K, B: Nb x K (both k-contiguous bf16).
// Store out[n*ldc + m] (m contiguous). OUTF: 0 bf16, 1 fp32.
// BNMODE: 0 none, 1 channel = m, 2 channel = n. RESID: += R[n*ldc+m] (bf16).
template<int OUTF, int BNMODE, int RESID, int LRELU>
__global__ __launch_bounds__(256)
void gemm_tn(const __hip_bfloat16* __restrict__ A, int lda, long sA,
             const __hip_bfloat16* __restrict__ B, int ldb, long sB,
             void* __restrict__ Cv, int ldc, long sC,
             const __hip_bfloat16* __restrict__ R, long sR,
             const float* __restrict__ bn, int bnlen, int Kd) {
  int bz = blockIdx.z;
  A += (long)bz * sA;
  B += (long)bz * sB;
  __shared__ __hip_bfloat16 As[128 * 32];
  __shared__ __hip_bfloat16 Bs[128 * 32];
  int t = threadIdx.x, lane = t & 63, w = t >> 6;
  int wm = w & 1, wn = w >> 1;
  long i0 = (long)blockIdx.x * 128, j0 = (long)blockIdx.y * 128;
  f32x4 acc[4][4];
#pragma unroll
  for (int i = 0; i < 4; ++i)
#pragma unroll
    for (int j = 0; j < 4; ++j) acc[i][j] = f32x4{0.f, 0.f, 0.f, 0.f};

  int srow = w * 16 + (lane >> 2);
  int sch  = (lane & 3) * 8;
  const __hip_bfloat16* ga0 = A + (i0 + srow) * lda + sch;
  const __hip_bfloat16* ga1 = A + (i0 + 64 + srow) * lda + sch;
  const __hip_bfloat16* gb0 = B + (j0 + srow) * ldb + sch;
  const __hip_bfloat16* gb1 = B + (j0 + 64 + srow) * ldb + sch;
  __hip_bfloat16* la0 = As + (w * 16) * 32;
  __hip_bfloat16* la1 = As + (64 + w * 16) * 32;
  __hip_bfloat16* lb0 = Bs + (w * 16) * 32;
  __hip_bfloat16* lb1 = Bs + (64 + w * 16) * 32;
  const __hip_bfloat16* pa = As + (wm * 64 + (lane & 15)) * 32 + (lane >> 4) * 8;
  const __hip_bfloat16* pb = Bs + (wn * 64 + (lane & 15)) * 32 + (lane >> 4) * 8;

  for (int k0 = 0; k0 < Kd; k0 += 32) {
    gll16(ga0, la0);
    gll16(ga1, la1);
    gll16(gb0, lb0);
    gll16(gb1, lb1);
    ga0 += 32; ga1 += 32; gb0 += 32; gb1 += 32;
    __syncthreads();
    bf16x8 af[4], bfv[4];
#pragma unroll
    for (int i = 0; i < 4; ++i) af[i]  = *(const bf16x8*)(pa + i * 16 * 32);
#pragma unroll
    for (int j = 0; j < 4; ++j) bfv[j] = *(const bf16x8*)(pb + j * 16 * 32);
#pragma unroll
    for (int i = 0; i < 4; ++i)
#pragma unroll
      for (int j = 0; j < 4; ++j)
        acc[i][j] = __builtin_amdgcn_mfma_f32_16x16x32_bf16(af[i], bfv[j], acc[i][j], 0, 0, 0);
    __syncthreads();
  }

  int mlocal = (lane >> 4) * 4;
  int nlocal = lane & 15;
#pragma unroll
  for (int i = 0; i < 4; ++i) {
    long m0 = i0 + wm * 64 + i * 16 + mlocal;
    float bsc[4], bsh[4];
    if (BNMODE == 1) {
#pragma unroll
      for (int r = 0; r < 4; ++r) {
        long c = m0 + r;
        float sc = bn[c] * rsqrtf(bn[3 * bnlen + c] + 1e-5f);
        bsc[r] = sc;
        bsh[r] = bn[bnlen + c] - bn[2 * bnlen + c] * sc;
      }
    }
#pragma unroll
    for (int j = 0; j < 4; ++j) {
      long nn = j0 + wn * 64 + j * 16 + nlocal;
      float sc2 = 1.f, sh2 = 0.f;
      if (BNMODE == 2) {
        sc2 = bn[nn] * rsqrtf(bn[3 * bnlen + nn] + 1e-5f);
        sh2 = bn[bnlen + nn] - bn[2 * bnlen + nn] * sc2;
      }
      f32x4 v = acc[i][j];
      float o4[4];
      ushort4 rv;
      if (RESID) rv = *(const ushort4*)(R + (long)bz * sR + nn * ldc + m0);
#pragma unroll
      for (int r = 0; r < 4; ++r) {
        float x = v[r];
        if (RESID) x += bf2f(r == 0 ? rv.x : r == 1 ? rv.y : r == 2 ? rv.z : rv.w);
        if (BNMODE == 1) x = x * bsc[r] + bsh[r];
        if (BNMODE == 2) x = x * sc2 + sh2;
        if (LRELU) x = (x >= 0.f) ? x : 0.2f * x;
        o4[r] = x;
      }
      if (OUTF) {
        float* Cp = (float*)Cv + (long)bz * sC + nn * ldc + m0;
        *(float4*)Cp = make_float4(o4[0], o4[1], o4[2], o4[3]);
      } else {
        __hip_bfloat16* Cp = (__hip_bfloat16*)Cv + (long)bz * sC + nn * ldc + m0;
        ushort4 sv;
        sv.x = f2bf(o4[0]); sv.y = f2bf(o4[1]); sv.z = f2bf(o4[2]); sv.w = f2bf(o4[3]);
        *(ushort4*)Cp = sv;
      }
    }
  }
}

// ----------------------------------------------------------- softmax ----
__global__ __launch_bounds__(256)
void softmax_bf(__hip_bfloat16* __restrict__ S) {
  long row = (long)blockIdx.y * Np + blockIdx.x;
  __hip_bfloat16* p = S + row * Np;
  int t = threadIdx.x;
  const float scale = 0.03125f;  // 1/sqrt(1024)
  float v[8];
  float mx = -3.4e38f;
#pragma unroll
  for (int u = 0; u < 8; ++u) {
    v[u] = __bfloat162float(p[u * 256 + t]) * scale;
    mx = fmaxf(mx, v[u]);
  }
  __shared__ float red[4];
#pragma unroll
  for (int off = 32; off > 0; off >>= 1) mx = fmaxf(mx, __shfl_xor(mx, off));
  if ((t & 63) == 0) red[t >> 6] = mx;
  __syncthreads();
  mx = fmaxf(fmaxf(red[0], red[1]), fmaxf(red[2], red[3]));
  __syncthreads();
  float sum = 0.f;
#pragma unroll
  for (int u = 0; u < 8; ++u) { v[u] = __expf(v[u] - mx); sum += v[u]; }
#pragma unroll
  for (int off = 32; off > 0; off >>= 1) sum += __shfl_xor(sum, off);
  if ((t & 63) == 0) red[t >> 6] = sum;
  __syncthreads();
  sum = red[0] + red[1] + red[2] + red[3];
  float inv = 1.f / sum;
#pragma unroll
  for (int u = 0; u < 8; ++u) p[u * 256 + t] = __float2bfloat16(v[u] * inv);
}

// ------------------------------------------------------------ launch ----
extern "C" void kernel_launch(void* const* d_in, const int* in_sizes, int n_in,
                              void* d_out, int out_size, void* d_ws, size_t ws_size,
                              hipStream_t stream) {
  const float* x       = (const float*)d_in[0];
  const float* ec1_w1  = (const float*)d_in[1];
  const float* ec1_bn1 = (const float*)d_in[2];
  const float* ec1_w2  = (const float*)d_in[3];
  const float* ec1_bn2 = (const float*)d_in[4];
  const float* ec2_w1  = (const float*)d_in[5];
  const float* ec2_bn1 = (const float*)d_in[6];
  const float* ec2_w2  = (const float*)d_in[7];
  const float* ec2_bn2 = (const float*)d_in[8];
  const float* ec3_w1  = (const float*)d_in[9];
  const float* ec3_bn1 = (const float*)d_in[10];
  const float* ec3_w2  = (const float*)d_in[11];
  const float* ec3_bn2 = (const float*)d_in[12];
  const float* emb_w   = (const float*)d_in[13];
  const float* q_w     = (const float*)d_in[14];
  const float* k_w     = (const float*)d_in[15];
  const float* v_w     = (const float*)d_in[16];
  const float* att_bn1 = (const float*)d_in[17];
  const float* ff_w1   = (const float*)d_in[18];
  const float* ff_w2   = (const float*)d_in[19];
  const float* att_bn2 = (const float*)d_in[20];
  const float* cb_w    = (const float*)d_in[21];
  const float* cb_bn   = (const float*)d_in[22];
  float* out = (float*)d_out;
  (void)in_sizes; (void)n_in; (void)out_size; (void)ws_size;

  // ---- workspace layout ----
  float* ws  = (float*)d_ws;
  float* xt  = ws;                        // [B,N,4] fp32       65,536
  float* f1  = xt + 65536;                // [B,N,64] fp32   1,048,576
  float* f2  = f1 + 1048576;              // [B,N,64] fp32   1,048,576
  float* sqb = f2 + 1048576;              // [B,N]              16,384
  int*   idxb = (int*)(sqb + 16384);      // [B,N,32]          524,288
  __hip_bfloat16* xc  = (__hip_bfloat16*)(idxb + 524288);  // [B,N,192] bf16
  __hip_bfloat16* wts = xc + 3145728;     // converted weights, 5,439,488 bf16
  float* big = (float*)(wts + 5439488);   // phase A: dist fp32 [B,N,N] (134MB)
  __hip_bfloat16* hb  = (__hip_bfloat16*)big;     // phase B: h   [B,N,1024]
  __hip_bfloat16* qb  = hb + 16777216;            //          q   [B,N,1024]
  __hip_bfloat16* kb  = qb + 16777216;            //          k   [B,N,1024] (later ff1 out)
  __hip_bfloat16* vtb = kb + 16777216;            //          v^T [B,1024,N]
  __hip_bfloat16* Sb  = vtb + 16777216;           //          S/P [B,N,N] bf16
  float* dist = big;
  float* biasb = big + 33554432;          // [B,N,64] fp32, after dist (phase A only)

  __hip_bfloat16* emb_wb = wts;
  __hip_bfloat16* q_wb   = wts + 196608;
  __hip_bfloat16* k_wb   = wts + 1245184;
  __hip_bfloat16* v_wb   = wts + 2293760;
  __hip_bfloat16* ff1_wb = wts + 3342336;
  __hip_bfloat16* ff2_wb = wts + 3866624;
  __hip_bfloat16* cb_wb  = wts + 4390912;

  const long sN1024 = (long)Np * 1024;
  const long sN512  = (long)Np * 512;
  const long sN192  = (long)Np * 192;
  const long sNN    = (long)Np * Np;

  // ---- weight conversion ----
  cvt_bf16_kernel<<<768,  256, 0, stream>>>(emb_w, emb_wb, 196608);
  cvt_bf16_kernel<<<4096, 256, 0, stream>>>(q_w,   q_wb,   1048576);
  cvt_bf16_kernel<<<4096, 256, 0, stream>>>(k_w,   k_wb,   1048576);
  cvt_bf16_kernel<<<4096, 256, 0, stream>>>(v_w,   v_wb,   1048576);
  cvt_bf16_kernel<<<2048, 256, 0, stream>>>(ff_w1, ff1_wb, 524288);
  cvt_bf16_kernel<<<2048, 256, 0, stream>>>(ff_w2, ff2_wb, 524288);
  cvt_bf16_kernel<<<4096, 256, 0, stream>>>(cb_w,  cb_wb,  1048576);

  // ---- transpose input ----
  xpose_kernel<<<64, 256, 0, stream>>>(x, xt);

  // ---- EdgeConv 1 ----
  sq_kernel<3, 4><<<64, 256, 0, stream>>>(xt, sqb);
  dist_kernel<<<dim3(16, 16, Bn), 256, 0, stream>>>(xt, 4, (long)Np * 4, dist, sNN, sqb, 3);
  topk_kernel<<<dim3(Np, Bn), 64, 0, stream>>>(dist, idxb);
  biasker<3, 4><<<dim3(Np / 32, Bn), 256, 0, stream>>>(xt, ec1_w1, biasb);
  edgeconv2<3, 4><<<dim3(Np / 2, Bn), 64, 0, stream>>>(
      xt, idxb, biasb, ec1_w1, ec1_bn1, ec1_w2, ec1_bn2, f1, xc);

  // ---- EdgeConv 2 ----
  sq_kernel<64, 64><<<64, 256, 0, stream>>>(f1, sqb);
  dist_kernel<<<dim3(16, 16, Bn), 256, 0, stream>>>(f1, 64, (long)Np * 64, dist, sNN, sqb, 64);
  topk_kernel<<<dim3(Np, Bn), 64, 0, stream>>>(dist, idxb);
  biasker<64, 64><<<dim3(Np / 32, Bn), 256, 0, stream>>>(f1, ec2_w1, biasb);
  edgeconv2<64, 64><<<dim3(Np / 2, Bn), 64, 0, stream>>>(
      f1, idxb, biasb, ec2_w1, ec2_bn1, ec2_w2, ec2_bn2, f2, xc + 64);

  // ---- EdgeConv 3 ----
  sq_kernel<64, 64><<<64, 256, 0, stream>>>(f2, sqb);
  dist_kernel<<<dim3(16, 16, Bn), 256, 0, stream>>>(f2, 64, (long)Np * 64, dist, sNN, sqb, 64);
  topk_kernel<<<dim3(Np, Bn), 64, 0, stream>>>(dist, idxb);
  biasker<64, 64><<<dim3(Np / 32, Bn), 256, 0, stream>>>(f2, ec3_w1, biasb);
  edgeconv2<64, 64><<<dim3(Np / 2, Bn), 64, 0, stream>>>(
      f2, idxb, biasb, ec3_w1, ec3_bn1, ec3_w2, ec3_bn2, nullptr, xc + 128);

  // ---- emb: h[n][c] = emb_w @ xc ----
  gemm_tn<0, 0, 0, 0><<<dim3(8, 16, Bn), 256, 0, stream>>>(
      emb_wb, 192, 0, xc, 192, sN192, hb, 1024, sN1024, nullptr, 0, nullptr, 0, 192);

  // ---- q, k (as [n][c]), v (as [c][n]) ----
  gemm_tn<0, 0, 0, 0><<<dim3(8, 16, Bn), 256, 0, stream>>>(
      q_wb, 1024, 0, hb, 1024, sN1024, qb, 1024, sN1024, nullptr, 0, nullptr, 0, 1024);
  gemm_tn<0, 0, 0, 0><<<dim3(8, 16, Bn), 256, 0, stream>>>(
      k_wb, 1024, 0, hb, 1024, sN1024, kb, 1024, sN1024, nullptr, 0, nullptr, 0, 1024);
  gemm_tn<0, 0, 0, 0><<<dim3(16, 8, Bn), 256, 0, stream>>>(
      hb, 1024, sN1024, v_wb, 1024, 0, vtb, 2048, sN1024, nullptr, 0, nullptr, 0, 1024);

  // ---- scores S[n][m] = k[m]·q[n], softmax rows ----
  gemm_tn<0, 0, 0, 0><<<dim3(16, 16, Bn), 256, 0, stream>>>(
      kb, 1024, sN1024, qb, 1024, sN1024, Sb, 2048, sNN, nullptr, 0, nullptr, 0, 1024);
  softmax_bf<<<dim3(Np, Bn), 256, 0, stream>>>(Sb);

  // ---- x_r[n][c] = sum_m P[n][m] vt[c][m]; h = bn1(h + x_r) in place ----
  gemm_tn<0, 1, 1, 0><<<dim3(8, 16, Bn), 256, 0, stream>>>(
      vtb, 2048, sN1024, Sb, 2048, sNN, hb, 1024, sN1024, hb, sN1024, att_bn1, 1024, 2048);

  // ---- ff1 (lrelu) into qb ----
  gemm_tn<0, 0, 0, 1><<<dim3(4, 16, Bn), 256, 0, stream>>>(
      ff1_wb, 1024, 0, hb, 1024, sN1024, qb, 512, sN512, nullptr, 0, nullptr, 0, 1024);
  // ---- ff2 + resid + bn2, in place on h ----
  gemm_tn<0, 1, 1, 0><<<dim3(8, 16, Bn), 256, 0, stream>>>(
      ff2_wb, 512, 0, qb, 512, sN512, hb, 1024, sN1024, hb, sN1024, att_bn2, 1024, 512);

  // ---- head: out[o][n] fp32 = lrelu(bn(cb_w @ h)) ----
  gemm_tn<1, 2, 0, 1><<<dim3(16, 8, Bn), 256, 0, stream>>>(
      hb, 1024, sN1024, cb_wb, 1024, 0, out, 2048, sN1024, nullptr, 0, cb_bn, 1024, 1024);
}

// Round 5
// 1540.419 us; speedup vs baseline: 1.2847x; 1.2847x over previous
//
#include <hip/hip_runtime.h>
#include <hip/hip_bf16.h>

constexpr int Bn  = 8;
constexpr int Np  = 2048;
constexpr int KNN = 32;

typedef __attribute__((ext_vector_type(8))) short bf16x8;
typedef __attribute__((ext_vector_type(4))) float f32x4;

__device__ static inline void gll16(const void* g, void* l) {
  __builtin_amdgcn_global_load_lds((const __attribute__((address_space(1))) void*)g,
                                   (__attribute__((address_space(3))) void*)l, 16, 0, 0);
}

__device__ static inline unsigned short f2bf(float x) {
  union { __hip_bfloat16 h; unsigned short u; } cv; cv.h = __float2bfloat16(x); return cv.u;
}
__device__ static inline float bf2f(unsigned short u) {
  union { __hip_bfloat16 h; unsigned short u; } cv; cv.u = u; return __bfloat162float(cv.h);
}

// ------------------------------------------------------------- helpers ----
__global__ __launch_bounds__(256)
void cvt_bf16_kernel(const float* __restrict__ s, __hip_bfloat16* __restrict__ d, int n) {
  int i = blockIdx.x * 256 + threadIdx.x;
  if (i < n) d[i] = __float2bfloat16(s[i]);
}

// W1a (first CIN cols of w1), zero-padded to K1, bf16.
template<int CIN, int K1>
__global__ __launch_bounds__(256)
void cvt_w1a(const float* __restrict__ w1, __hip_bfloat16* __restrict__ out) {
  int i = blockIdx.x * 256 + threadIdx.x;
  if (i >= 64 * K1) return;
  int o = i / K1, c = i - o * K1;
  out[i] = __float2bfloat16(c < CIN ? w1[o * 2 * CIN + c] : 0.f);
}

__global__ __launch_bounds__(256)
void xpose_kernel(const float* __restrict__ x, float* __restrict__ xt,
                  __hip_bfloat16* __restrict__ xb) {
  int i = blockIdx.x * 256 + threadIdx.x;   // over B*N
  int b = i >> 11, n = i & 2047;
  const float* p = x + (long)b * 3 * Np + n;
  float vx = p[0], vy = p[Np], vz = p[2 * Np];
  xt[(long)i * 4 + 0] = vx;
  xt[(long)i * 4 + 1] = vy;
  xt[(long)i * 4 + 2] = vz;
  xt[(long)i * 4 + 3] = 0.f;
  __hip_bfloat16* q = xb + (long)i * 8;
  q[0] = __float2bfloat16(vx); q[1] = __float2bfloat16(vy);
  q[2] = __float2bfloat16(vz);
  q[3] = __float2bfloat16(0.f); q[4] = q[3]; q[5] = q[3]; q[6] = q[3]; q[7] = q[3];
}

template<int C, int CP>
__global__ __launch_bounds__(256)
void sq_kernel(const float* __restrict__ f, float* __restrict__ out) {
  int i = blockIdx.x * 256 + threadIdx.x;   // over B*N
  const float* p = f + (long)i * CP;
  float s = 0.f;
#pragma unroll
  for (int c = 0; c < C; ++c) s += p[c] * p[c];
  out[i] = s;
}

// -------------------------------------------------- fp32 dist GEMM ----
__global__ __launch_bounds__(256)
void dist_kernel(const float* __restrict__ A, int lda, long sA,
                 float* __restrict__ C, long sC,
                 const float* __restrict__ sqB, int Kd) {
  int bz = blockIdx.z;
  A += (long)bz * sA;
  C += (long)bz * sC;
  sqB += (long)bz * Np;
  int i0 = blockIdx.y * 128, j0 = blockIdx.x * 128;
  __shared__ float As[8][128];
  __shared__ float Bs[8][128];
  float acc[8][8];
#pragma unroll
  for (int a = 0; a < 8; ++a)
#pragma unroll
    for (int b2 = 0; b2 < 8; ++b2) acc[a][b2] = 0.f;
  int t = threadIdx.x;
  int tx = t & 15, ty = t >> 4;
  for (int k0 = 0; k0 < Kd; k0 += 8) {
    {
      int ii = t >> 1, kk = (t & 1) * 4;
#pragma unroll
      for (int u = 0; u < 4; ++u) {
        int kg = k0 + kk + u;
        As[kk + u][ii] = (kg < Kd) ? A[(long)(i0 + ii) * lda + kg] : 0.f;
        Bs[kk + u][ii] = (kg < Kd) ? A[(long)(j0 + ii) * lda + kg] : 0.f;
      }
    }
    __syncthreads();
#pragma unroll
    for (int kk = 0; kk < 8; ++kk) {
      float av[8], bv[8];
#pragma unroll
      for (int u = 0; u < 8; ++u) av[u] = As[kk][ty * 8 + u];
#pragma unroll
      for (int u = 0; u < 8; ++u) bv[u] = Bs[kk][tx * 8 + u];
#pragma unroll
      for (int a = 0; a < 8; ++a)
#pragma unroll
        for (int b2 = 0; b2 < 8; ++b2) acc[a][b2] += av[a] * bv[b2];
    }
    __syncthreads();
  }
#pragma unroll
  for (int a = 0; a < 8; ++a) {
    int i = i0 + ty * 8 + a;
#pragma unroll
    for (int b2 = 0; b2 < 8; ++b2) {
      int j = j0 + tx * 8 + b2;
      C[(long)i * Np + j] = sqB[j] - 2.f * acc[a][b2];
    }
  }
}

// -------------------------------------------------------------- topk ----
__global__ __launch_bounds__(64)
void topk_kernel(const float* __restrict__ D, int* __restrict__ idxOut) {
  long row = (long)blockIdx.y * Np + blockIdx.x;
  const float* rowp = D + row * Np;
  int lane = threadIdx.x;
  __shared__ unsigned long long buf[64 * 33];

  unsigned long long key[32];
  const float4* rp = (const float4*)(rowp + lane * 32);
#pragma unroll
  for (int j4 = 0; j4 < 8; ++j4) {
    float4 f4 = rp[j4];
    float fv[4] = {f4.x, f4.y, f4.z, f4.w};
#pragma unroll
    for (int u = 0; u < 4; ++u) {
      int m = lane * 32 + j4 * 4 + u;
      unsigned b = __float_as_uint(fv[u]);
      unsigned ou = (b & 0x80000000u) ? ~b : (b | 0x80000000u);
      key[j4 * 4 + u] = ((unsigned long long)ou << 32) | (unsigned)m;
    }
  }
#pragma unroll
  for (int k = 2; k <= 32; k <<= 1) {
#pragma unroll
    for (int j = k >> 1; j > 0; j >>= 1) {
#pragma unroll
      for (int i = 0; i < 32; ++i) {
        int l = i ^ j;
        if (l > i) {
          bool up = ((i & k) == 0);
          unsigned long long a = key[i], c = key[l];
          bool swp = up ? (a > c) : (a < c);
          unsigned long long lo = swp ? c : a;
          unsigned long long hi = swp ? a : c;
          key[i] = lo; key[l] = hi;
        }
      }
    }
  }
#pragma unroll
  for (int i = 0; i < 32; ++i) buf[i * 64 + lane] = key[i];

  unsigned long long h = key[0];
  int p = 1;
  int res = 0;
  for (int t = 0; t < KNN; ++t) {
    unsigned hh = (unsigned)(h >> 32), hl = (unsigned)h;
    unsigned g = hh;
#pragma unroll
    for (int off = 32; off > 0; off >>= 1)
      g = min(g, (unsigned)__shfl_xor((int)g, off));
    unsigned lo = (hh == g) ? hl : 0xFFFFFFFFu;
#pragma unroll
    for (int off = 32; off > 0; off >>= 1)
      lo = min(lo, (unsigned)__shfl_xor((int)lo, off));
    if (lane == t) res = (int)lo;
    if (hh == g && hl == lo) {
      h = buf[p * 64 + lane];
      ++p;
    }
  }
  if (lane < KNN) idxOut[row * KNN + lane] = res;
}

// -------------------------------------------------------------- bias ----
// bias[n][o] = sum_c (W1b - W1a)[o][c] * feat[n][c]  (folded center term, fp32)
template<int CIN, int CP>
__global__ __launch_bounds__(256)
void biasker(const float* __restrict__ feat, const float* __restrict__ w1,
             float* __restrict__ bias) {
  __shared__ float wd[64][CIN + 1];
  int tid = threadIdx.x;
  for (int e = tid; e < 64 * CIN; e += 256) {
    int o = e / CIN, c = e - o * CIN;
    wd[o][c] = w1[o * 2 * CIN + CIN + c] - w1[o * 2 * CIN + c];
  }
  __syncthreads();
  int wv = tid >> 6, o = tid & 63;
  float wr_[CIN];
#pragma unroll
  for (int c = 0; c < CIN; ++c) wr_[c] = wd[o][c];
  long base = (long)blockIdx.y * Np + blockIdx.x * 32 + wv * 8;
  for (int p = 0; p < 8; ++p) {
    const float* fr = feat + (base + p) * CP;
    float acc = 0.f;
#pragma unroll
    for (int c = 0; c < CIN; ++c) acc = fmaf(wr_[c], fr[c], acc);
    bias[(base + p) * 64 + o] = acc;
  }
}

// ------------------------------------------------------ fused edge MFMA ----
// Block = 4 points = 128 edge rows, 4 waves (wave w <-> point w).
// H1 = gathered_nbr @ W1a^T + bias -> bn1+lrelu (bf16, LDS)
// H2 = H1 @ W2^T -> bn2+lrelu (fp32, LDS, overwrites A|H1) -> maxpool over k.
template<int K1>   // padded input K: 32 (CIN=3) or 64
__global__ __launch_bounds__(256)
void edge_mfma(const __hip_bfloat16* __restrict__ featb, int fstride,
               const int* __restrict__ idx, const float* __restrict__ bias,
               const __hip_bfloat16* __restrict__ w1b,   // [64][K1] bf16
               const __hip_bfloat16* __restrict__ w2b,   // [64][64] bf16
               const float* __restrict__ bn1, const float* __restrict__ bn2,
               float* __restrict__ fout, __hip_bfloat16* __restrict__ xcseg) {
  __shared__ __align__(16) char lds[32768 + 64 * K1 * 2 + 8192 + 1024 + 512];
  __hip_bfloat16* A  = (__hip_bfloat16*)lds;             // [128][K1]
  __hip_bfloat16* H1 = A + 128 * K1;                     // [128][64]
  float*          H2 = (float*)lds;                      // [128][64] (reuse)
  __hip_bfloat16* W1 = (__hip_bfloat16*)(lds + 32768);   // [64][K1]
  __hip_bfloat16* W2 = W1 + 64 * K1;                     // [64][64]
  float* biasS = (float*)(lds + 32768 + 64 * K1 * 2 + 8192);  // [4][64]
  int*   idxS  = (int*)(biasS + 256);                    // [128]

  int t = threadIdx.x, lane = t & 63, w = t >> 6;
  long pb = (long)blockIdx.y * Np;
  int p0 = blockIdx.x * 4;

  if (t < 128) idxS[t] = idx[(pb + p0 + (t >> 5)) * KNN + (t & 31)];
  biasS[w * 64 + lane] = bias[(pb + p0 + w) * 64 + lane];
  // stage weights (16B chunks)
  for (int e = t; e < 64 * K1 / 8; e += 256)
    ((ulonglong2*)W1)[e] = ((const ulonglong2*)w1b)[e];
  for (int e = t; e < 512; e += 256)
    ((ulonglong2*)W2)[e] = ((const ulonglong2*)w2b)[e];
  __syncthreads();

  // gather neighbor rows into A
  if (K1 == 64) {
#pragma unroll
    for (int i = 0; i < 4; ++i) {
      int e = t + i * 256;              // 1024 chunks of 16B
      int r = e >> 3, cc = e & 7;
      const ulonglong2* src = (const ulonglong2*)(featb + (pb + idxS[r]) * fstride) + cc;
      ((ulonglong2*)(A + r * 64))[cc] = *src;
    }
  } else {
    if (t < 128) {
      int r = t;
      ulonglong2 z; z.x = 0; z.y = 0;
      ((ulonglong2*)(A + r * 32))[0] = *(const ulonglong2*)(featb + (pb + idxS[r]) * fstride);
      ((ulonglong2*)(A + r * 32))[1] = z;
      ((ulonglong2*)(A + r * 32))[2] = z;
      ((ulonglong2*)(A + r * 32))[3] = z;
    }
  }

  // per-lane bn constants for its 4 output-channel columns
  int ocol = lane & 15;
  float sc1[4], sh1[4], sc2[4], sh2[4];
#pragma unroll
  for (int jn = 0; jn < 4; ++jn) {
    int o = jn * 16 + ocol;
    sc1[jn] = bn1[o] * rsqrtf(bn1[192 + o] + 1e-5f);
    sh1[jn] = bn1[64 + o] - bn1[128 + o] * sc1[jn];
    sc2[jn] = bn2[o] * rsqrtf(bn2[192 + o] + 1e-5f);
    sh2[jn] = bn2[64 + o] - bn2[128 + o] * sc2[jn];
  }
  __syncthreads();

  int mrow = lane & 15;
  int kc   = (lane >> 4) * 8;
  constexpr int KS = K1 / 32;

  // GEMM1
  f32x4 acc[2][4];
#pragma unroll
  for (int im = 0; im < 2; ++im)
#pragma unroll
    for (int jn = 0; jn < 4; ++jn) acc[im][jn] = f32x4{0.f, 0.f, 0.f, 0.f};
#pragma unroll
  for (int s = 0; s < KS; ++s) {
    bf16x8 af[2], bf_[4];
#pragma unroll
    for (int im = 0; im < 2; ++im)
      af[im] = *(const bf16x8*)(A + (w * 32 + im * 16 + mrow) * K1 + s * 32 + kc);
#pragma unroll
    for (int jn = 0; jn < 4; ++jn)
      bf_[jn] = *(const bf16x8*)(W1 + (jn * 16 + mrow) * K1 + s * 32 + kc);
#pragma unroll
    for (int im = 0; im < 2; ++im)
#pragma unroll
      for (int jn = 0; jn < 4; ++jn)
        acc[im][jn] = __builtin_amdgcn_mfma_f32_16x16x32_bf16(af[im], bf_[jn], acc[im][jn], 0, 0, 0);
  }
  // epilogue 1 -> H1 (bias + bn1 + lrelu, bf16)
#pragma unroll
  for (int im = 0; im < 2; ++im)
#pragma unroll
    for (int jn = 0; jn < 4; ++jn) {
      int o = jn * 16 + ocol;
      float bsv = biasS[w * 64 + o];
#pragma unroll
      for (int r = 0; r < 4; ++r) {
        int m = w * 32 + im * 16 + (lane >> 4) * 4 + r;
        float x = (acc[im][jn][r] + bsv) * sc1[jn] + sh1[jn];
        x = fmaxf(x, 0.2f * x);
        H1[m * 64 + o] = __float2bfloat16(x);
      }
    }
  __syncthreads();

  // GEMM2: preload frags from H1/W2, then barrier so H2 can overwrite
  bf16x8 a2[2][2], b2[4][2];
#pragma unroll
  for (int im = 0; im < 2; ++im)
#pragma unroll
    for (int s = 0; s < 2; ++s)
      a2[im][s] = *(const bf16x8*)(H1 + (w * 32 + im * 16 + mrow) * 64 + s * 32 + kc);
#pragma unroll
  for (int jn = 0; jn < 4; ++jn)
#pragma unroll
    for (int s = 0; s < 2; ++s)
      b2[jn][s] = *(const bf16x8*)(W2 + (jn * 16 + mrow) * 64 + s * 32 + kc);
  __syncthreads();

  f32x4 acc2[2][4];
#pragma unroll
  for (int im = 0; im < 2; ++im)
#pragma unroll
    for (int jn = 0; jn < 4; ++jn) acc2[im][jn] = f32x4{0.f, 0.f, 0.f, 0.f};
#pragma unroll
  for (int s = 0; s < 2; ++s)
#pragma unroll
    for (int im = 0; im < 2; ++im)
#pragma unroll
      for (int jn = 0; jn < 4; ++jn)
        acc2[im][jn] = __builtin_amdgcn_mfma_f32_16x16x32_bf16(a2[im][s], b2[jn][s], acc2[im][jn], 0, 0, 0);
  // epilogue 2 -> H2 (bn2 + lrelu, fp32)
#pragma unroll
  for (int im = 0; im < 2; ++im)
#pragma unroll
    for (int jn = 0; jn < 4; ++jn) {
      int o = jn * 16 + ocol;
#pragma unroll
      for (int r = 0; r < 4; ++r) {
        int m = w * 32 + im * 16 + (lane >> 4) * 4 + r;
        float x = acc2[im][jn][r] * sc2[jn] + sh2[jn];
        x = fmaxf(x, 0.2f * x);
        H2[m * 64 + o] = x;
      }
    }
  __syncthreads();

  // maxpool over 32 edges of point w (thread t: point t>>6, channel t&63)
  {
    int o = t & 63;
    float m = -3.4e38f;
#pragma unroll
    for (int k = 0; k < 32; ++k) m = fmaxf(m, H2[(w * 32 + k) * 64 + o]);
    int n2 = p0 + w;
    if (fout) fout[(pb + n2) * 64 + o] = m;
    xcseg[(pb + n2) * 192 + o] = __float2bfloat16(m);
  }
}

// ------------------------------------------------------ bf16 TN GEMM ----
template<int OUTF, int BNMODE, int RESID, int LRELU>
__global__ __launch_bounds__(256)
void gemm_tn(const __hip_bfloat16* __restrict__ A, int lda, long sA,
             const __hip_bfloat16* __restrict__ B, int ldb, long sB,
             void* __restrict__ Cv, int ldc, long sC,
             const __hip_bfloat16* __restrict__ R, long sR,
             const float* __restrict__ bn, int bnlen, int Kd) {
  int bz = blockIdx.z;
  A += (long)bz * sA;
  B += (long)bz * sB;
  __shared__ __hip_bfloat16 As[128 * 32];
  __shared__ __hip_bfloat16 Bs[128 * 32];
  int t = threadIdx.x, lane = t & 63, w = t >> 6;
  int wm = w & 1, wn = w >> 1;
  long i0 = (long)blockIdx.x * 128, j0 = (long)blockIdx.y * 128;
  f32x4 acc[4][4];
#pragma unroll
  for (int i = 0; i < 4; ++i)
#pragma unroll
    for (int j = 0; j < 4; ++j) acc[i][j] = f32x4{0.f, 0.f, 0.f, 0.f};

  int srow = w * 16 + (lane >> 2);
  int sch  = (lane & 3) * 8;
  const __hip_bfloat16* ga0 = A + (i0 + srow) * lda + sch;
  const __hip_bfloat16* ga1 = A + (i0 + 64 + srow) * lda + sch;
  const __hip_bfloat16* gb0 = B + (j0 + srow) * ldb + sch;
  const __hip_bfloat16* gb1 = B + (j0 + 64 + srow) * ldb + sch;
  __hip_bfloat16* la0 = As + (w * 16) * 32;
  __hip_bfloat16* la1 = As + (64 + w * 16) * 32;
  __hip_bfloat16* lb0 = Bs + (w * 16) * 32;
  __hip_bfloat16* lb1 = Bs + (64 + w * 16) * 32;
  const __hip_bfloat16* pa = As + (wm * 64 + (lane & 15)) * 32 + (lane >> 4) * 8;
  const __hip_bfloat16* pb = Bs + (wn * 64 + (lane & 15)) * 32 + (lane >> 4) * 8;

  for (int k0 = 0; k0 < Kd; k0 += 32) {
    gll16(ga0, la0);
    gll16(ga1, la1);
    gll16(gb0, lb0);
    gll16(gb1, lb1);
    ga0 += 32; ga1 += 32; gb0 += 32; gb1 += 32;
    __syncthreads();
    bf16x8 af[4], bfv[4];
#pragma unroll
    for (int i = 0; i < 4; ++i) af[i]  = *(const bf16x8*)(pa + i * 16 * 32);
#pragma unroll
    for (int j = 0; j < 4; ++j) bfv[j] = *(const bf16x8*)(pb + j * 16 * 32);
#pragma unroll
    for (int i = 0; i < 4; ++i)
#pragma unroll
      for (int j = 0; j < 4; ++j)
        acc[i][j] = __builtin_amdgcn_mfma_f32_16x16x32_bf16(af[i], bfv[j], acc[i][j], 0, 0, 0);
    __syncthreads();
  }

  int mlocal = (lane >> 4) * 4;
  int nlocal = lane & 15;
#pragma unroll
  for (int i = 0; i < 4; ++i) {
    long m0 = i0 + wm * 64 + i * 16 + mlocal;
    float bsc[4], bsh[4];
    if (BNMODE == 1) {
#pragma unroll
      for (int r = 0; r < 4; ++r) {
        long c = m0 + r;
        float sc = bn[c] * rsqrtf(bn[3 * bnlen + c] + 1e-5f);
        bsc[r] = sc;
        bsh[r] = bn[bnlen + c] - bn[2 * bnlen + c] * sc;
      }
    }
#pragma unroll
    for (int j = 0; j < 4; ++j) {
      long nn = j0 + wn * 64 + j * 16 + nlocal;
      float sc2 = 1.f, sh2 = 0.f;
      if (BNMODE == 2) {
        sc2 = bn[nn] * rsqrtf(bn[3 * bnlen + nn] + 1e-5f);
        sh2 = bn[bnlen + nn] - bn[2 * bnlen + nn] * sc2;
      }
      f32x4 v = acc[i][j];
      float o4[4];
      ushort4 rv;
      if (RESID) rv = *(const ushort4*)(R + (long)bz * sR + nn * ldc + m0);
#pragma unroll
      for (int r = 0; r < 4; ++r) {
        float x = v[r];
        if (RESID) x += bf2f(r == 0 ? rv.x : r == 1 ? rv.y : r == 2 ? rv.z : rv.w);
        if (BNMODE == 1) x = x * bsc[r] + bsh[r];
        if (BNMODE == 2) x = x * sc2 + sh2;
        if (LRELU) x = (x >= 0.f) ? x : 0.2f * x;
        o4[r] = x;
      }
      if (OUTF) {
        float* Cp = (float*)Cv + (long)bz * sC + nn * ldc + m0;
        *(float4*)Cp = make_float4(o4[0], o4[1], o4[2], o4[3]);
      } else {
        __hip_bfloat16* Cp = (__hip_bfloat16*)Cv + (long)bz * sC + nn * ldc + m0;
        ushort4 sv;
        sv.x = f2bf(o4[0]); sv.y = f2bf(o4[1]); sv.z = f2bf(o4[2]); sv.w = f2bf(o4[3]);
        *(ushort4*)Cp = sv;
      }
    }
  }
}

// ----------------------------------------------------------- softmax ----
__global__ __launch_bounds__(256)
void softmax_bf(__hip_bfloat16* __restrict__ S) {
  long row = (long)blockIdx.y * Np + blockIdx.x;
  __hip_bfloat16* p = S + row * Np;
  int t = threadIdx.x;
  const float scale = 0.03125f;  // 1/sqrt(1024)
  float v[8];
  float mx = -3.4e38f;
#pragma unroll
  for (int u = 0; u < 8; ++u) {
    v[u] = __bfloat162float(p[u * 256 + t]) * scale;
    mx = fmaxf(mx, v[u]);
  }
  __shared__ float red[4];
#pragma unroll
  for (int off = 32; off > 0; off >>= 1) mx = fmaxf(mx, __shfl_xor(mx, off));
  if ((t & 63) == 0) red[t >> 6] = mx;
  __syncthreads();
  mx = fmaxf(fmaxf(red[0], red[1]), fmaxf(red[2], red[3]));
  __syncthreads();
  float sum = 0.f;
#pragma unroll
  for (int u = 0; u < 8; ++u) { v[u] = __expf(v[u] - mx); sum += v[u]; }
#pragma unroll
  for (int off = 32; off > 0; off >>= 1) sum += __shfl_xor(sum, off);
  if ((t & 63) == 0) red[t >> 6] = sum;
  __syncthreads();
  sum = red[0] + red[1] + red[2] + red[3];
  float inv = 1.f / sum;
#pragma unroll
  for (int u = 0; u < 8; ++u) p[u * 256 + t] = __float2bfloat16(v[u] * inv);
}

// ------------------------------------------------------------ launch ----
extern "C" void kernel_launch(void* const* d_in, const int* in_sizes, int n_in,
                              void* d_out, int out_size, void* d_ws, size_t ws_size,
                              hipStream_t stream) {
  const float* x       = (const float*)d_in[0];
  const float* ec1_w1  = (const float*)d_in[1];
  const float* ec1_bn1 = (const float*)d_in[2];
  const float* ec1_w2  = (const float*)d_in[3];
  const float* ec1_bn2 = (const float*)d_in[4];
  const float* ec2_w1  = (const float*)d_in[5];
  const float* ec2_bn1 = (const float*)d_in[6];
  const float* ec2_w2  = (const float*)d_in[7];
  const float* ec2_bn2 = (const float*)d_in[8];
  const float* ec3_w1  = (const float*)d_in[9];
  const float* ec3_bn1 = (const float*)d_in[10];
  const float* ec3_w2  = (const float*)d_in[11];
  const float* ec3_bn2 = (const float*)d_in[12];
  const float* emb_w   = (const float*)d_in[13];
  const float* q_w     = (const float*)d_in[14];
  const float* k_w     = (const float*)d_in[15];
  const float* v_w     = (const float*)d_in[16];
  const float* att_bn1 = (const float*)d_in[17];
  const float* ff_w1   = (const float*)d_in[18];
  const float* ff_w2   = (const float*)d_in[19];
  const float* att_bn2 = (const float*)d_in[20];
  const float* cb_w    = (const float*)d_in[21];
  const float* cb_bn   = (const float*)d_in[22];
  float* out = (float*)d_out;
  (void)in_sizes; (void)n_in; (void)out_size; (void)ws_size;

  // ---- workspace layout ----
  float* ws  = (float*)d_ws;
  float* xt  = ws;                        // [B,N,4] fp32       65,536
  float* f1  = xt + 65536;                // [B,N,64] fp32   1,048,576
  float* f2  = f1 + 1048576;              // [B,N,64] fp32   1,048,576
  float* sqb = f2 + 1048576;              // [B,N]              16,384
  int*   idxb = (int*)(sqb + 16384);      // [B,N,32]          524,288
  __hip_bfloat16* xc  = (__hip_bfloat16*)(idxb + 524288);  // [B,N,192] bf16
  __hip_bfloat16* wts = xc + 3145728;     // converted weights, 5,439,488 bf16
  __hip_bfloat16* ew  = wts + 5439488;    // edge weights bf16, 22,528
  __hip_bfloat16* xb  = ew + 22528;       // [B,N,8] bf16, 131,072
  float* big = (float*)(xb + 131072);     // phase A: dist fp32 [B,N,N] (134MB)
  __hip_bfloat16* hb  = (__hip_bfloat16*)big;     // phase B: h   [B,N,1024]
  __hip_bfloat16* qb  = hb + 16777216;            //          q   [B,N,1024]
  __hip_bfloat16* kb  = qb + 16777216;            //          k   [B,N,1024]
  __hip_bfloat16* vtb = kb + 16777216;            //          v^T [B,1024,N]
  __hip_bfloat16* Sb  = vtb + 16777216;           //          S/P [B,N,N] bf16
  float* dist = big;
  float* biasb = big + 33554432;          // [B,N,64] fp32 (phase A only)

  __hip_bfloat16* emb_wb = wts;
  __hip_bfloat16* q_wb   = wts + 196608;
  __hip_bfloat16* k_wb   = wts + 1245184;
  __hip_bfloat16* v_wb   = wts + 2293760;
  __hip_bfloat16* ff1_wb = wts + 3342336;
  __hip_bfloat16* ff2_wb = wts + 3866624;
  __hip_bfloat16* cb_wb  = wts + 4390912;

  __hip_bfloat16* w1a1_b = ew;            // [64][32]  2048
  __hip_bfloat16* w2_1b  = ew + 2048;     // [64][64]  4096
  __hip_bfloat16* w1a2_b = ew + 6144;     // [64][64]  4096
  __hip_bfloat16* w2_2b  = ew + 10240;    // [64][64]  4096
  __hip_bfloat16* w1a3_b = ew + 14336;    // [64][64]  4096
  __hip_bfloat16* w2_3b  = ew + 18432;    // [64][64]  4096

  const long sN1024 = (long)Np * 1024;
  const long sN512  = (long)Np * 512;
  const long sN192  = (long)Np * 192;
  const long sNN    = (long)Np * Np;

  // ---- weight conversion ----
  cvt_bf16_kernel<<<768,  256, 0, stream>>>(emb_w, emb_wb, 196608);
  cvt_bf16_kernel<<<4096, 256, 0, stream>>>(q_w,   q_wb,   1048576);
  cvt_bf16_kernel<<<4096, 256, 0, stream>>>(k_w,   k_wb,   1048576);
  cvt_bf16_kernel<<<4096, 256, 0, stream>>>(v_w,   v_wb,   1048576);
  cvt_bf16_kernel<<<2048, 256, 0, stream>>>(ff_w1, ff1_wb, 524288);
  cvt_bf16_kernel<<<2048, 256, 0, stream>>>(ff_w2, ff2_wb, 524288);
  cvt_bf16_kernel<<<4096, 256, 0, stream>>>(cb_w,  cb_wb,  1048576);
  cvt_w1a<3, 32><<<8, 256, 0, stream>>>(ec1_w1, w1a1_b);
  cvt_w1a<64, 64><<<16, 256, 0, stream>>>(ec2_w1, w1a2_b);
  cvt_w1a<64, 64><<<16, 256, 0, stream>>>(ec3_w1, w1a3_b);
  cvt_bf16_kernel<<<16, 256, 0, stream>>>(ec1_w2, w2_1b, 4096);
  cvt_bf16_kernel<<<16, 256, 0, stream>>>(ec2_w2, w2_2b, 4096);
  cvt_bf16_kernel<<<16, 256, 0, stream>>>(ec3_w2, w2_3b, 4096);

  // ---- transpose input (fp32 [B,N,4] + bf16 [B,N,8]) ----
  xpose_kernel<<<64, 256, 0, stream>>>(x, xt, xb);

  // ---- EdgeConv 1 ----
  sq_kernel<3, 4><<<64, 256, 0, stream>>>(xt, sqb);
  dist_kernel<<<dim3(16, 16, Bn), 256, 0, stream>>>(xt, 4, (long)Np * 4, dist, sNN, sqb, 3);
  topk_kernel<<<dim3(Np, Bn), 64, 0, stream>>>(dist, idxb);
  biasker<3, 4><<<dim3(Np / 32, Bn), 256, 0, stream>>>(xt, ec1_w1, biasb);
  edge_mfma<32><<<dim3(Np / 4, Bn), 256, 0, stream>>>(
      xb, 8, idxb, biasb, w1a1_b, w2_1b, ec1_bn1, ec1_bn2, f1, xc);

  // ---- EdgeConv 2 ----
  sq_kernel<64, 64><<<64, 256, 0, stream>>>(f1, sqb);
  dist_kernel<<<dim3(16, 16, Bn), 256, 0, stream>>>(f1, 64, (long)Np * 64, dist, sNN, sqb, 64);
  topk_kernel<<<dim3(Np, Bn), 64, 0, stream>>>(dist, idxb);
  biasker<64, 64><<<dim3(Np / 32, Bn), 256, 0, stream>>>(f1, ec2_w1, biasb);
  edge_mfma<64><<<dim3(Np / 4, Bn), 256, 0, stream>>>(
      xc, 192, idxb, biasb, w1a2_b, w2_2b, ec2_bn1, ec2_bn2, f2, xc + 64);

  // ---- EdgeConv 3 ----
  sq_kernel<64, 64><<<64, 256, 0, stream>>>(f2, sqb);
  dist_kernel<<<dim3(16, 16, Bn), 256, 0, stream>>>(f2, 64, (long)Np * 64, dist, sNN, sqb, 64);
  topk_kernel<<<dim3(Np, Bn), 64, 0, stream>>>(dist, idxb);
  biasker<64, 64><<<dim3(Np / 32, Bn), 256, 0, stream>>>(f2, ec3_w1, biasb);
  edge_mfma<64><<<dim3(Np / 4, Bn), 256, 0, stream>>>(
      xc + 64, 192, idxb, biasb, w1a3_b, w2_3b, ec3_bn1, ec3_bn2, nullptr, xc + 128);

  // ---- emb: h[n][c] = emb_w @ xc ----
  gemm_tn<0, 0, 0, 0><<<dim3(8, 16, Bn), 256, 0, stream>>>(
      emb_wb, 192, 0, xc, 192, sN192, hb, 1024, sN1024, nullptr, 0, nullptr, 0, 192);

  // ---- q, k (as [n][c]), v (as [c][n]) ----
  gemm_tn<0, 0, 0, 0><<<dim3(8, 16, Bn), 256, 0, stream>>>(
      q_wb, 1024, 0, hb, 1024, sN1024, qb, 1024, sN1024, nullptr, 0, nullptr, 0, 1024);
  gemm_tn<0, 0, 0, 0><<<dim3(8, 16, Bn), 256, 0, stream>>>(
      k_wb, 1024, 0, hb, 1024, sN1024, kb, 1024, sN1024, nullptr, 0, nullptr, 0, 1024);
  gemm_tn<0, 0, 0, 0><<<dim3(16, 8, Bn), 256, 0, stream>>>(
      hb, 1024, sN1024, v_wb, 1024, 0, vtb, 2048, sN1024, nullptr, 0, nullptr, 0, 1024);

  // ---- scores S[n][m] = k[m]·q[n], softmax rows ----
  gemm_tn<0, 0, 0, 0><<<dim3(16, 16, Bn), 256, 0, stream>>>(
      kb, 1024, sN1024, qb, 1024, sN1024, Sb, 2048, sNN, nullptr, 0, nullptr, 0, 1024);
  softmax_bf<<<dim3(Np, Bn), 256, 0, stream>>>(Sb);

  // ---- x_r[n][c] = sum_m P[n][m] vt[c][m]; h = bn1(h + x_r) in place ----
  gemm_tn<0, 1, 1, 0><<<dim3(8, 16, Bn), 256, 0, stream>>>(
      vtb, 2048, sN1024, Sb, 2048, sNN, hb, 1024, sN1024, hb, sN1024, att_bn1, 1024, 2048);

  // ---- ff1 (lrelu) into qb ----
  gemm_tn<0, 0, 0, 1><<<dim3(4, 16, Bn), 256, 0, stream>>>(
      ff1_wb, 1024, 0, hb, 1024, sN1024, qb, 512, sN512, nullptr, 0, nullptr, 0, 1024);
  // ---- ff2 + resid + bn2, in place on h ----
  gemm_tn<0, 1, 1, 0><<<dim3(8, 16, Bn), 256, 0, stream>>>(
      ff2_wb, 512, 0, qb, 512, sN512, hb, 1024, sN1024, hb, sN1024, att_bn2, 1024, 512);

  // ---- head: out[o][n] fp32 = lrelu(bn(cb_w @ h)) ----
  gemm_tn<1, 2, 0, 1><<<dim3(16, 8, Bn), 256, 0, stream>>>(
      hb, 1024, sN1024, cb_wb, 1024, 0, out, 2048, sN1024, nullptr, 0, cb_bn, 1024, 1024);
}